// Round 5
// baseline (14.321 us; speedup 1.0000x reference)
//
#include <hip/hip_runtime.h>

#define Bb 128
#define Cc 400
#define Ll 100
#define Pp 16

// ---------------------------------------------------------------------------
// Fused kernel, l-quad split (R4 structure) + wave-uniform support guards.
//
// Key fact: w[i][l] != 0 only for i in [s, e]  (q = 16s + d*l + j covers
// [16s, 16e); i0 = q>>4 in [s, e-1]; part2 extends to e; clip never fires
// since q_max = 16e-1 <= 1583 < 1584). s,e are per-block uniform -> all
// guards are scalar compares + s_cbranch, no divergence. This skips ~65%
// of the ds_read+FMA work and the x float4-chunks outside [s>>2, e>>2].
//
// Phase 1 (unchanged, proven): 16x100 weight matrix in LDS via closed form,
// all 1600 entries written (zeros outside the support — safety net).
// Phase 2: thread (c, h=l-quad): acc[4] static; per in-range i: one
// ds_read_b128 of w[i][h*4..h*4+3] (4 distinct addrs/wave, banks 0..15,
// conflict-free broadcast) and 4 FMAs.
//
// Weight derivation (per b,l): q_j = 16*s + d*l + j (j in [0,d)), pos = q+8,
// t = (min(pos,1592)-8)/16, i0 = min(floor(t),98), fr = t-i0.
// w[i] = [sum_{i0_j==i}(1-fr_j) + sum_{i0_j==i-1}(fr_j)] / max(d,1),
// each piece a contiguous q-range -> triangular-number closed form.
// ---------------------------------------------------------------------------
__global__ __launch_bounds__(256) void TemporalPooling_fused_kernel(
    const float* __restrict__ x, const int* __restrict__ seg,
    float* __restrict__ out) {
  __shared__ float w[Ll * Pp];   // [i][l], 6.4 KiB

  const int b   = blockIdx.y;
  const int tid = threadIdx.x;

  const int s = seg[2 * b];
  const int e = seg[2 * b + 1];
  const int d = e - s;
  const float inv = 1.0f / (float)max(d, 1);

  // ---- phase 1: weights into LDS (all 1600 entries) ----
  for (int idx = tid; idx < Ll * Pp; idx += 256) {
    const int i = idx >> 4;   // 0..99
    const int l = idx & 15;   // 0..15

    const int a  = 16 * s + d * l;   // q_0
    const int ad = a + d;            // q end (exclusive)

    float sum = 0.0f;

    const int base1 = 16 * i;
    {  // j with i0 == i : q in [16i,16i+16) ∩ [a,ad) ∩ [0,1584)
      const int lo = max(base1, a);
      const int hi = min(min(base1 + 16, ad), 1584);
      const int n = hi - lo;
      if (n > 0) {
        const int sq = (hi * (hi - 1) - lo * (lo - 1)) >> 1;
        sum += (float)n - (float)(sq - n * base1) * 0.0625f;
      }
    }
    {  // j with i0 == i-1 : q in [16(i-1),16i) ∩ [a,ad) ∩ [0,1584)
      const int base2 = base1 - 16;
      const int lo = max(base2, a);
      const int hi = min(min(base1, ad), 1584);
      const int n = hi - lo;
      if (n > 0) {
        const int sq = (hi * (hi - 1) - lo * (lo - 1)) >> 1;
        sum += (float)(sq - n * base2) * 0.0625f;
      }
    }
    if (i == Ll - 1) {  // clipped tail (never fires for these shapes; kept)
      const int nclip = ad - max(a, 1584);
      if (nclip > 0) sum += (float)nclip;
    }

    w[idx] = sum * inv;
  }
  __syncthreads();

  // ---- phase 2: one thread per (channel, l-quad), support-guarded ----
  const int r = tid >> 2;                 // 0..63 channel within tile
  const int h = tid & 3;                  // l-quad id
  const int c = blockIdx.x * 64 + r;
  if (c >= Cc) return;

  const float4* x4 = (const float4*)(x + ((size_t)b * Cc + c) * Ll);
  const float* wh = &w[h * 4];            // base + i*64B immediate offsets

  float a0 = 0.0f, a1 = 0.0f, a2 = 0.0f, a3 = 0.0f;

#pragma unroll
  for (int q = 0; q < 25; ++q) {
    // uniform chunk guard: does [4q, 4q+3] intersect [s, e]?
    if (4 * q + 3 < s || 4 * q > e) continue;     // scalar skip
    const float4 xc = x4[q];
#pragma unroll
    for (int k = 0; k < 4; ++k) {
      const int i = q * 4 + k;
      if (i < s || i > e) continue;               // uniform edge trim
      const float xs = (k == 0) ? xc.x : (k == 1) ? xc.y : (k == 2) ? xc.z
                                                                    : xc.w;
      const float4 wv = *(const float4*)&wh[i * 16];  // ds_read_b128
      a0 = fmaf(wv.x, xs, a0);
      a1 = fmaf(wv.y, xs, a1);
      a2 = fmaf(wv.z, xs, a2);
      a3 = fmaf(wv.w, xs, a3);
    }
  }

  float4* o4 = (float4*)(out + ((size_t)b * Cc + c) * Pp + h * 4);
  *o4 = make_float4(a0, a1, a2, a3);
}

extern "C" void kernel_launch(void* const* d_in, const int* in_sizes, int n_in,
                              void* d_out, int out_size, void* d_ws,
                              size_t ws_size, hipStream_t stream) {
  const float* x = (const float*)d_in[0];   // (128,400,100) fp32
  const int* seg = (const int*)d_in[1];     // (128,2) int32
  float* out = (float*)d_out;               // (128,400,16) fp32
  (void)d_ws; (void)ws_size;                // no workspace use

  dim3 grid((Cc + 63) / 64, Bb);            // (7, 128) = 896 blocks
  TemporalPooling_fused_kernel<<<grid, 256, 0, stream>>>(x, seg, out);
}

// Round 6
// 10.666 us; speedup vs baseline: 1.3427x; 1.3427x over previous
//
#include <hip/hip_runtime.h>

#define Bb 128
#define Cc 400
#define Ll 100
#define Pp 16
#define KP 128       // K padded to 4 MFMA k-steps
#define WS 136       // wT row stride (elements): 272B -> 2-way LDS conflict max

typedef __attribute__((ext_vector_type(8))) short short8;  // 8 bf16 (4 VGPR)
typedef __attribute__((ext_vector_type(4))) float f32x4;

// fp32 -> bf16, round-to-nearest-even, branchless (NaN irrelevant here)
static __device__ __forceinline__ unsigned short f2bf(float f) {
  unsigned int u = __float_as_uint(f);
  u += 0x7fffu + ((u >> 16) & 1u);
  return (unsigned short)(u >> 16);
}

// ---------------------------------------------------------------------------
// MFMA formulation: out[b] (400x16) = x[b] (400x100) . w[b] (100x16).
// Phase 1: closed-form w -> bf16 wT[l][i] in LDS (i padded to 128, natural 0
//          outside support). Phase 2: per wave, one 16x16 output tile via
//          4 x mfma_f32_16x16x32_bf16 over the padded K.
//
// Fragment layouts (gfx950, guide §3): A: row=lane&15, k=8*(lane>>4)+j;
// B: col=lane&15, k=8*(lane>>4)+j  (read as one ds_read_b128 from wT row);
// D: col=lane&15, row=4*(lane>>4)+v.
//
// Weight closed form (per b,l): q_j = 16*s + d*l + j (j in [0,d)),
// t=(min(q+8,1592)-8)/16, i0=min(floor(t),98), fr=t-i0;
// w[i] = [sum_{i0==i}(1-fr) + sum_{i0==i-1}(fr)] / max(d,1);
// each piece a contiguous q-range -> triangular-number sums.
// ---------------------------------------------------------------------------
__global__ __launch_bounds__(256) void TemporalPooling_mfma_kernel(
    const float* __restrict__ x, const int* __restrict__ seg,
    float* __restrict__ out) {
  __shared__ unsigned short wT[Pp * WS];   // [l][i], bf16, 4352 B

  const int b   = blockIdx.y;
  const int tid = threadIdx.x;

  const int s = seg[2 * b];
  const int e = seg[2 * b + 1];
  const int d = e - s;
  const float inv = 1.0f / (float)max(d, 1);

  // ---- phase 1: weights (bf16, transposed) into LDS; 2048/256 = 8 iters ----
  for (int idx = tid; idx < Pp * KP; idx += 256) {
    const int i = idx >> 4;    // 0..127 (>=100 -> closed form gives 0)
    const int l = idx & 15;

    const int a  = 16 * s + d * l;
    const int ad = a + d;

    float sum = 0.0f;
    const int base1 = 16 * i;
    {  // i0 == i : q in [16i,16i+16) ∩ [a,ad) ∩ [0,1584)
      const int lo = max(base1, a);
      const int hi = min(min(base1 + 16, ad), 1584);
      const int n = hi - lo;
      if (n > 0) {
        const int sq = (hi * (hi - 1) - lo * (lo - 1)) >> 1;
        sum += (float)n - (float)(sq - n * base1) * 0.0625f;
      }
    }
    {  // i0 == i-1 : q in [16(i-1),16i) ∩ [a,ad) ∩ [0,1584)
      const int base2 = base1 - 16;
      const int lo = max(base2, a);
      const int hi = min(min(base1, ad), 1584);
      const int n = hi - lo;
      if (n > 0) {
        const int sq = (hi * (hi - 1) - lo * (lo - 1)) >> 1;
        sum += (float)(sq - n * base2) * 0.0625f;
      }
    }
    if (i == Ll - 1) {  // clip tail (never fires for these shapes; kept)
      const int nclip = ad - max(a, 1584);
      if (nclip > 0) sum += (float)nclip;
    }

    wT[l * WS + i] = f2bf(sum * inv);
  }
  __syncthreads();

  // ---- phase 2: one 16x16 output tile per wave ----
  const int wave = tid >> 6;
  const int lane = tid & 63;
  const int tile = blockIdx.x * 4 + wave;      // 0..27; 25 tiles cover 400 ch
  if (tile >= (Cc / 16)) return;

  const int arow = lane & 15;   // A row (channel offset) / B & D column
  const int g    = lane >> 4;   // k-group

  const float* xrow = x + ((size_t)b * Cc + tile * 16 + arow) * Ll;

  f32x4 acc = {0.f, 0.f, 0.f, 0.f};
#pragma unroll
  for (int t = 0; t < 4; ++t) {
    const int k0 = t * 32 + g * 8;
    float xf[8];
    if (k0 < Ll) {                       // k0 in {0,...,96}: float4 is in-bounds
      const float4 v = *(const float4*)(xrow + k0);
      xf[0] = v.x; xf[1] = v.y; xf[2] = v.z; xf[3] = v.w;
    } else {
      xf[0] = xf[1] = xf[2] = xf[3] = 0.f;
    }
    if (k0 + 4 < Ll) {
      const float4 v = *(const float4*)(xrow + k0 + 4);
      xf[4] = v.x; xf[5] = v.y; xf[6] = v.z; xf[7] = v.w;
    } else {
      xf[4] = xf[5] = xf[6] = xf[7] = 0.f;
    }

    short8 afrag;
#pragma unroll
    for (int j = 0; j < 8; ++j) afrag[j] = (short)f2bf(xf[j]);

    const short8 bfrag =
        *(const short8*)&wT[arow * WS + t * 32 + g * 8];  // ds_read_b128

    acc = __builtin_amdgcn_mfma_f32_16x16x32_bf16(afrag, bfrag, acc, 0, 0, 0);
  }

  // ---- epilogue: D[row=4g+v][col=arow] -> out[b, tile*16+4g+v, arow] ----
  float* obase = out + (((size_t)b * Cc + tile * 16 + g * 4) * Pp) + arow;
#pragma unroll
  for (int v = 0; v < 4; ++v) obase[v * Pp] = acc[v];
}

extern "C" void kernel_launch(void* const* d_in, const int* in_sizes, int n_in,
                              void* d_out, int out_size, void* d_ws,
                              size_t ws_size, hipStream_t stream) {
  const float* x = (const float*)d_in[0];   // (128,400,100) fp32
  const int* seg = (const int*)d_in[1];     // (128,2) int32
  float* out = (float*)d_out;               // (128,400,16) fp32
  (void)d_ws; (void)ws_size;

  dim3 grid((Cc / 16 + 3) / 4, Bb);         // (7, 128)
  TemporalPooling_mfma_kernel<<<grid, 256, 0, stream>>>(x, seg, out);
}